// Round 8
// baseline (21.274 us; speedup 1.0000x reference)
//
#include <hip/hip_runtime.h>
#include <math.h>

#define BATCH 2
#define LLEN  2080
#define MCH   2
#define TT    51
#define FF    80
#define HOP   40
#define KW    1600
#define OUTL  2040
#define NT    640
#define NS    52                   // output strips of 40 samples
#define NB    (BATCH * NS * MCH)   // 208 blocks
#define ZROW  161                  // padded Z row stride (float2)
#define PI_F  3.14159265358979323846f

// One block per (b, strip s, m). Computes delta spectra of frames s and s-1
// (with roll wraparound), their iDFT halves, overlap-add, residual, slice.
__global__ __launch_bounds__(NT) void mono_kernel(
    const float* __restrict__ xr, const float* __restrict__ xi,
    const float* __restrict__ ti,
    const float* __restrict__ wr, const float* __restrict__ wi,
    const float* __restrict__ br, const float* __restrict__ bi,
    float* __restrict__ out, int out_size)
{
    __shared__ float2 xs[4 * FF];        // samples for 4 frame slots
    __shared__ float2 tw[FF];            // e^{+i 2pi r/80} exact (iDFT)
    __shared__ float2 Ysh[4][2 * FF];    // double-stored spectra, 4 slots
    __shared__ float2 Wsh[KW];           // w [n1][n2], reg-staged
    __shared__ float2 Zall[2][40][ZROW]; // Z rows for deltas A,B (overlaid later)
    __shared__ float2 dvec[2 * FF];      // two delta spectra

    float2* flat = &Zall[0][0][0];       // 12880-entry overlay scratch

    int tid = threadIdx.x;
    int bid = blockIdx.x;
    int b   = bid / (NS * MCH);
    int rem = bid % (NS * MCH);
    int s   = rem / MCH;
    int mi  = rem % MCH;

    bool dAv = (s <= TT - 1);            // delta[s] exists
    bool dBv = (s >= 1);                 // delta[s-1] exists
    int tA  = dAv ? s : 0;               // dummy-safe
    int tAp = (tA + TT - 1) % TT;        // roll: prev(0)=50
    int tB  = dBv ? s - 1 : 0;
    int tBp = (tB + TT - 1) % TT;

    float bre = br[0], bim = bi[0];

    // ---- w reg-stage (latency hides under phases 1-2) ----
    float2 wreg0 = make_float2(wr[tid],      wi[tid]);
    float2 wreg1 = make_float2(wr[tid + NT], wi[tid + NT]);
    float2 wreg2 = make_float2(0.f, 0.f);
    if (tid < KW - 2 * NT)
        wreg2 = make_float2(wr[tid + 2 * NT], wi[tid + 2 * NT]);

    // ---- Phase 0: samples for 4 slots (320 thr) + tw table (80 thr) ----
    if (tid < 4 * FF) {
        int slot = tid / FF, j = tid % FF;
        int tslot = (slot == 0) ? tA : (slot == 1) ? tAp : (slot == 2) ? tB : tBp;
        int g = (b * LLEN + tslot * HOP + j) * MCH + mi;
        xs[tid] = make_float2(xr[g], xi[g]);
    } else if (tid < 4 * FF + FF) {
        int jj = tid - 4 * FF;
        float sn, cs;
        sincosf((2.0f * PI_F / FF) * (float)jj, &sn, &cs);
        tw[jj] = make_float2(cs, sn);
    }
    __syncthreads();   // A

    // ---- Phase 1: STFT of 4 slots; 320 outputs x 2 partials x 40 MACs ----
    {
        int o    = tid >> 1;      // 0..319
        int pq   = tid & 1;
        int slot = o / FF;
        int ff   = o % FF;
        const float2* xb = &xs[slot * FF];

        // seed at j0 = pq*40: e^{-i pi ff pq} = +/-1 exact
        float2 tv = ((ff & pq) & 1) ? make_float2(-1.f, 0.f) : make_float2(1.f, 0.f);
        float sp, cp;
        sincosf(-(2.0f * PI_F / FF) * (float)ff, &sp, &cp);
        float2 st = make_float2(cp, sp);     // e^{-i 2pi ff/80}

        float2 a = make_float2(0.f, 0.f);
        int j = pq * 40;
        #pragma unroll 4
        for (int i = 0; i < 40; ++i, ++j) {
            float2 xv = xb[j];
            a.x += xv.x * tv.x - xv.y * tv.y;
            a.y += xv.x * tv.y + xv.y * tv.x;
            float nx = tv.x * st.x - tv.y * st.y;
            tv.y = tv.x * st.y + tv.y * st.x;
            tv.x = nx;
        }
        a.x += __shfl_xor(a.x, 1);
        a.y += __shfl_xor(a.y, 1);
        if (pq == 0) {
            Ysh[slot][ff + 20] = a;
            Ysh[slot][(ff < 60) ? (ff + 100) : (ff - 60)] = a;
        }
    }
    __syncthreads();   // B

    // ---- Phase 2: Z rows for both deltas (6400 values, 10/thread) ----
    #pragma unroll
    for (int i = 0; i < 10; ++i) {
        int zi = tid + i * NT;        // 0..6399
        int d  = zi / 3200;
        int rr = zi % 3200;
        int jn = rr / FF;
        int g  = rr % FF;
        const float2* Ya = Ysh[2 * d];
        const float2* Yp = Ysh[2 * d + 1];
        float2 a  = Ya[g + 20], bm = Ya[g - jn + 40];
        float2 cc = Yp[g + 20], dm = Yp[g - jn + 40];
        float zre = a.x * bm.x + a.y * bm.y + cc.x * dm.x + cc.y * dm.y;
        float zim = a.y * bm.x - a.x * bm.y + cc.y * dm.x - cc.x * dm.y;
        float2 z = make_float2(zre, zim);
        Zall[d][jn][g + 20] = z;
        Zall[d][jn][(g < 60) ? (g + 100) : (g - 60)] = z;
    }
    // stage W into LDS (global loads long since landed)
    Wsh[tid]      = wreg0;
    Wsh[tid + NT] = wreg1;
    if (tid < KW - 2 * NT) Wsh[tid + 2 * NT] = wreg2;
    __syncthreads();   // C

    // ---- Phase 3: both deltas; 10-wide register sliding window over n1 ----
    {
        int d  = tid / 320;           // which delta
        int rr = tid % 320;
        int jn = rr >> 3;             // n2 index 0..39
        int fg = rr & 7;
        int fb = fg * 10;
        const float2* zz = &Zall[d][jn][0];
        const float2* Ya = Ysh[2 * d];

        float2 S[10], W[10];
        #pragma unroll
        for (int q = 0; q < 10; ++q) { S[q] = make_float2(0.f, 0.f); W[q] = zz[fb + 40 + q]; }
        #pragma unroll
        for (int jn1 = 0; jn1 < 40; ++jn1) {
            float2 wv = Wsh[jn1 * 40 + jn];
            #pragma unroll
            for (int q = 0; q < 10; ++q) {
                S[q].x += wv.x * W[q].x - wv.y * W[q].y;
                S[q].y += wv.x * W[q].y + wv.y * W[q].x;
            }
            if (jn1 < 39) {
                #pragma unroll
                for (int q = 9; q > 0; --q) W[q] = W[q - 1];
                W[0] = zz[fb + 39 - jn1];
            }
        }
        float2 O[10];
        #pragma unroll
        for (int q = 0; q < 10; ++q) {
            float2 y = Ya[fb + q - jn + 40];   // Y[(f - n2) % 80]
            O[q] = make_float2(y.x * S[q].x - y.y * S[q].y,
                               y.x * S[q].y + y.y * S[q].x);
        }
        __syncthreads();   // D: all Zall reads done before overlay writes
        #pragma unroll
        for (int q = 0; q < 10; ++q)
            flat[d * 3200 + jn * 80 + fb + q] = O[q];
    }
    __syncthreads();   // E

    // ---- tree-reduce n2: stage 1 (640 thr, 10 rows each) ----
    {
        int d  = tid / 320;
        int rr = tid % 320;
        int p  = rr / FF;   // 0..3
        int f  = rr % FF;
        float2 sum = make_float2(0.f, 0.f);
        #pragma unroll
        for (int q = 0; q < 10; ++q) {
            float2 v = flat[d * 3200 + (p * 10 + q) * 80 + f];
            sum.x += v.x; sum.y += v.y;
        }
        flat[6400 + d * 320 + p * 80 + f] = sum;
    }
    __syncthreads();   // F
    if (tid < 160) {
        int d = tid / FF, f = tid % FF;
        float2 sum = make_float2(bre, bim);
        #pragma unroll
        for (int p = 0; p < 4; ++p) {
            float2 v = flat[6400 + d * 320 + p * 80 + f];
            sum.x += v.x; sum.y += v.y;
        }
        dvec[d * FF + f] = sum;
    }
    __syncthreads();   // G

    // ---- Phase 4: half-iDFTs; (d, 40 samples, 8 partials) x 10 MACs ----
    {
        int d   = tid / 320;
        int rr  = tid % 320;
        int j40 = rr >> 3;
        int p8  = rr & 7;
        int j   = j40 + 40 * d;       // frame A: j in [0,40); frame B: [40,80)
        float2 a = make_float2(0.f, 0.f);
        int f0 = p8 * 10;
        int r  = (j * f0) % FF;
        #pragma unroll 5
        for (int i = 0; i < 10; ++i) {
            float2 dv = dvec[d * FF + f0 + i];
            float2 tv = tw[r];        // e^{+i 2pi j f/80}
            a.x += dv.x * tv.x - dv.y * tv.y;
            a.y += dv.x * tv.y + dv.y * tv.x;
            r += j; if (r >= FF) r -= FF;
        }
        flat[(d * 40 + j40) * 8 + p8] = a;
    }
    __syncthreads();   // H

    // ---- final: overlap-add + cov + residual + slice, 40 threads ----
    if (tid < 40) {
        int j40 = tid;
        int l = 40 * s + j40;
        if (l >= 20 && l < LLEN - 20) {
            float2 acc = make_float2(0.f, 0.f);
            float cov = 0.f;
            if (dAv) {
                #pragma unroll
                for (int p = 0; p < 8; ++p) {
                    float2 v = flat[j40 * 8 + p];
                    acc.x += v.x; acc.y += v.y;
                }
                cov += 1.f;
            }
            if (dBv) {
                #pragma unroll
                for (int p = 0; p < 8; ++p) {
                    float2 v = flat[(40 + j40) * 8 + p];
                    acc.x += v.x; acc.y += v.y;
                }
                cov += 1.f;
            }
            float P   = exp2f(ti[b * 4] * 0.33219280948873623f) * 0.5f;  // 10^(x/10)/m
            float inv = 1.0f / ((float)FF * cov);
            float ar = acc.x * inv, ai = acc.y * inv;
            int gi = (b * LLEN + l) * MCH + mi;
            int lo = l - 20;
            int p  = (b * OUTL + lo) * MCH + mi;
            const int tot = BATCH * OUTL * MCH;
            float outr = xr[gi] + ar * P;
            if (out_size == tot) {
                out[p] = outr;
            } else {
                out[p * 2]     = outr;
                out[p * 2 + 1] = xi[gi] + ai * P;
            }
        }
    }
}

extern "C" void kernel_launch(void* const* d_in, const int* in_sizes, int n_in,
                              void* d_out, int out_size, void* d_ws, size_t ws_size,
                              hipStream_t stream)
{
    const float* xr = (const float*)d_in[0];
    const float* xi = (const float*)d_in[1];
    const float* ti = (const float*)d_in[2];
    const float* wr = (const float*)d_in[3];
    const float* wi = (const float*)d_in[4];
    const float* br = (const float*)d_in[5];
    const float* bi = (const float*)d_in[6];

    mono_kernel<<<NB, NT, 0, stream>>>(xr, xi, ti, wr, wi, br, bi,
                                       (float*)d_out, out_size);
}